// Round 1
// 146.627 us; speedup vs baseline: 1.1144x; 1.1144x over previous
//
#include <hip/hip_runtime.h>
#include <hip/hip_fp16.h>

#define NNODES 100000
#define KNBR 32
#define IN_C 128
#define OUT_C 64

// ===========================================================================
// Kernel 1: h = x @ W^T via MFMA (bf16 hi/lo split, fp16 store)
// Block = 256 threads (4 waves). Wave handles 32 nodes (two 16-row frags),
// block handles 128 nodes, full 64 output channels.
// 3-product split: x*W ~= xh*wh + xl*wh + xh*wl  (xl*wl ~ 2^-18, dropped).
// A-fragments load directly from global (16B/lane chunks, line-coalesced).
// W is converted once per block into LDS (hi & lo planes).
// ===========================================================================

typedef __attribute__((ext_vector_type(8))) short bf16x8;
typedef __attribute__((ext_vector_type(4))) float f32x4;

__device__ __forceinline__ unsigned short bf16_rne(float f) {
    unsigned u = __builtin_bit_cast(unsigned, f);
    u = (u + 0x7FFFu + ((u >> 16) & 1u)) >> 16;
    return (unsigned short)u;
}
__device__ __forceinline__ float bf16_f(unsigned short s) {
    unsigned u = ((unsigned)s) << 16;
    return __builtin_bit_cast(float, u);
}

__device__ __forceinline__ void split8(const float4& u, const float4& v,
                                       bf16x8& hi, bf16x8& lo) {
    const float f[8] = {u.x, u.y, u.z, u.w, v.x, v.y, v.z, v.w};
#pragma unroll
    for (int j = 0; j < 8; ++j) {
        const unsigned short hb = bf16_rne(f[j]);
        hi[j] = (short)hb;
        lo[j] = (short)bf16_rne(f[j] - bf16_f(hb));
    }
}

// W LDS row stride: 136 elems = 272 B = 17*16 B. Keeps b128 alignment and
// rotates the 16B slot by one per row -> <=2-way bank aliasing (free).
#define GW_LD 136

__global__ __launch_bounds__(256) void gemm_h_kernel(
    const float* __restrict__ x, const float* __restrict__ W,
    __half* __restrict__ h)
{
    __shared__ __align__(16) unsigned short swh[64 * GW_LD];
    __shared__ __align__(16) unsigned short swl[64 * GW_LD];

    const int t = threadIdx.x;

    // ---- stage W as bf16 hi/lo into LDS (once per block) ----
#pragma unroll
    for (int i = 0; i < 8; ++i) {
        const int e   = t + 256 * i;        // float4 index, 2048 total
        const int row = e >> 5;             // 32 float4s per 128-float row
        const int c4  = (e & 31) * 4;
        const float4 wv = *(const float4*)(W + row * IN_C + c4);
        ushort4 ph, pl;
        ph.x = bf16_rne(wv.x); pl.x = bf16_rne(wv.x - bf16_f(ph.x));
        ph.y = bf16_rne(wv.y); pl.y = bf16_rne(wv.y - bf16_f(ph.y));
        ph.z = bf16_rne(wv.z); pl.z = bf16_rne(wv.z - bf16_f(ph.z));
        ph.w = bf16_rne(wv.w); pl.w = bf16_rne(wv.w - bf16_f(ph.w));
        *(ushort4*)(swh + row * GW_LD + c4) = ph;
        *(ushort4*)(swl + row * GW_LD + c4) = pl;
    }
    __syncthreads();

    const int lane = t & 63;
    const int w    = t >> 6;
    const int r    = lane & 15;   // A-frag row / B-frag col / C-frag col
    const int g    = lane >> 4;   // k-chunk within frag (8 elems each)
    const int nb   = blockIdx.x * 128 + 32 * w;

    f32x4 acc[2][4];
#pragma unroll
    for (int i = 0; i < 2; ++i)
#pragma unroll
        for (int c = 0; c < 4; ++c) acc[i][c] = (f32x4){0.f, 0.f, 0.f, 0.f};

    int n0 = nb + r;       if (n0 > NNODES - 1) n0 = NNODES - 1;
    int n1 = nb + 16 + r;  if (n1 > NNODES - 1) n1 = NNODES - 1;
    const float* px0 = x + (size_t)n0 * IN_C;
    const float* px1 = x + (size_t)n1 * IN_C;

#pragma unroll
    for (int ks = 0; ks < 4; ++ks) {
        const int k0 = 32 * ks + 8 * g;
        const float4 u0 = *(const float4*)(px0 + k0);
        const float4 v0 = *(const float4*)(px0 + k0 + 4);
        const float4 u1 = *(const float4*)(px1 + k0);
        const float4 v1 = *(const float4*)(px1 + k0 + 4);
        bf16x8 a0h, a0l, a1h, a1l;
        split8(u0, v0, a0h, a0l);
        split8(u1, v1, a1h, a1l);
#pragma unroll
        for (int c = 0; c < 4; ++c) {
            const int wrow = 16 * c + r;
            const bf16x8 bh = *(const bf16x8*)(swh + wrow * GW_LD + k0);
            const bf16x8 bl = *(const bf16x8*)(swl + wrow * GW_LD + k0);
            acc[0][c] = __builtin_amdgcn_mfma_f32_16x16x32_bf16(a0h, bh, acc[0][c], 0, 0, 0);
            acc[1][c] = __builtin_amdgcn_mfma_f32_16x16x32_bf16(a1h, bh, acc[1][c], 0, 0, 0);
            acc[0][c] = __builtin_amdgcn_mfma_f32_16x16x32_bf16(a0l, bh, acc[0][c], 0, 0, 0);
            acc[1][c] = __builtin_amdgcn_mfma_f32_16x16x32_bf16(a1l, bh, acc[1][c], 0, 0, 0);
            acc[0][c] = __builtin_amdgcn_mfma_f32_16x16x32_bf16(a0h, bl, acc[0][c], 0, 0, 0);
            acc[1][c] = __builtin_amdgcn_mfma_f32_16x16x32_bf16(a1h, bl, acc[1][c], 0, 0, 0);
        }
    }

    // C layout (m89-verified): col = lane&15, row = (lane>>4)*4 + i
#pragma unroll
    for (int rf = 0; rf < 2; ++rf) {
#pragma unroll
        for (int i = 0; i < 4; ++i) {
            const int node = nb + 16 * rf + 4 * g + i;
            if (node < NNODES) {
                __half* ph = h + (size_t)node * OUT_C + r;
#pragma unroll
                for (int c = 0; c < 4; ++c)
                    ph[16 * c] = __float2half(acc[rf][c][i]);
            }
        }
    }
}

// ======================= Kernel 2: gather + rank-15-of-32 ==================
// Packed half2 min/max via gfx950 VOP3P — ROCm 7.2 headers lack __hmin2/__hmax2.
__device__ __forceinline__ unsigned pk_min(unsigned a, unsigned b) {
    unsigned d;
    asm("v_pk_min_f16 %0, %1, %2" : "=v"(d) : "v"(a), "v"(b));
    return d;
}
__device__ __forceinline__ unsigned pk_max(unsigned a, unsigned b) {
    unsigned d;
    asm("v_pk_max_f16 %0, %1, %2" : "=v"(d) : "v"(a), "v"(b));
    return d;
}
__device__ __forceinline__ void ce(unsigned& a, unsigned& b) {
    const unsigned lo = pk_min(a, b);
    b = pk_max(a, b);
    a = lo;
}

// Batcher odd-even mergesort, n=16, 63 comparators (hardcoded list).
__device__ __forceinline__ void sort16(unsigned* v) {
    constexpr unsigned char net[63][2] = {
        {0,1},{2,3},{4,5},{6,7},{8,9},{10,11},{12,13},{14,15},
        {0,2},{1,3},{4,6},{5,7},{8,10},{9,11},{12,14},{13,15},
        {1,2},{5,6},{9,10},{13,14},
        {0,4},{1,5},{2,6},{3,7},{8,12},{9,13},{10,14},{11,15},
        {2,4},{3,5},{10,12},{11,13},
        {1,2},{3,4},{5,6},{9,10},{11,12},{13,14},
        {0,8},{1,9},{2,10},{3,11},{4,12},{5,13},{6,14},{7,15},
        {4,8},{5,9},{6,10},{7,11},
        {2,4},{3,5},{6,8},{7,9},{10,12},{11,13},
        {1,2},{3,4},{5,6},{7,8},{9,10},{11,12},{13,14}
    };
#pragma unroll
    for (int i = 0; i < 63; ++i) ce(v[net[i][0]], v[net[i][1]]);
}

// rank 15 (0-indexed) of 32 values: sort both 16-halves, then a pruned
// Batcher odd-even merge that materializes only output 15.
__device__ __forceinline__ unsigned median32(unsigned* v) {
    sort16(v);
    sort16(v + 16);
    const unsigned* A = v;
    const unsigned* B = v + 16;
    const unsigned e2a = pk_max(pk_max(A[0], B[0]), pk_min(A[8],  B[8]));
    const unsigned o1a = pk_min(pk_max(A[4], B[4]), pk_min(A[12], B[12]));
    const unsigned Ep4 = pk_max(e2a, o1a);
    const unsigned e2b = pk_max(pk_max(A[2], B[2]), pk_min(A[10], B[10]));
    const unsigned o1b = pk_min(pk_max(A[6], B[6]), pk_min(A[14], B[14]));
    const unsigned Op3 = pk_min(e2b, o1b);
    const unsigned E8  = pk_max(Ep4, Op3);
    const unsigned e2c = pk_max(pk_max(A[1], B[1]), pk_min(A[9],  B[9]));
    const unsigned o1c = pk_min(pk_max(A[5], B[5]), pk_min(A[13], B[13]));
    const unsigned Ep4o = pk_max(e2c, o1c);
    const unsigned e2d = pk_max(pk_max(A[3], B[3]), pk_min(A[11], B[11]));
    const unsigned o1d = pk_min(pk_max(A[7], B[7]), pk_min(A[15], B[15]));
    const unsigned Op3o = pk_min(e2d, o1d);
    const unsigned O7  = pk_min(Ep4o, Op3o);
    return pk_min(E8, O7);
}

// 32 lanes per node; each lane owns 2 channels as ONE packed-half2 stream.
// Halves live register state vs the 4-channel version (a[32] only) ->
// ~2x occupancy for gather-latency hiding. Each gather instruction reads a
// full 128B h-row per 32-lane group (2 rows per wave-instruction).
__global__ __launch_bounds__(256) void median_kernel(
    const __half* __restrict__ h, const int* __restrict__ nbrs,
    float* __restrict__ out)
{
    const int t = threadIdx.x;
    const int li   = t & 31;
    const int node = blockIdx.x * 8 + (t >> 5);
    const int ch0  = 2 * li;

    const int idx = nbrs[node * KNBR + li];   // coalesced: wave covers 2 nodes

    unsigned a[KNBR];
#pragma unroll
    for (int k = 0; k < KNBR; ++k) {
        const int row = __shfl(idx, k, 32);
        a[k] = *(const unsigned*)(h + row * OUT_C + ch0);
    }

    const unsigned m = median32(a);
    const __half2 hm = *(const __half2*)&m;
    float2 o;
    o.x = __low2float(hm);
    o.y = __high2float(hm);
    *(float2*)(out + node * OUT_C + ch0) = o;
}

extern "C" void kernel_launch(void* const* d_in, const int* in_sizes, int n_in,
                              void* d_out, int out_size, void* d_ws, size_t ws_size,
                              hipStream_t stream) {
    (void)in_sizes; (void)n_in; (void)out_size; (void)ws_size;
    const float* x    = (const float*)d_in[0];
    const int*   nbrs = (const int*)d_in[1];
    const float* W    = (const float*)d_in[2];
    float* out = (float*)d_out;
    __half* h  = (__half*)d_ws;   // 100000*64*2 = 12.8 MB scratch

    gemm_h_kernel<<<(NNODES + 127) / 128, 256, 0, stream>>>(x, W, h);
    median_kernel<<<NNODES / 8, 256, 0, stream>>>(h, nbrs, out);
}

// Round 3
// 146.503 us; speedup vs baseline: 1.1153x; 1.0008x over previous
//
#include <hip/hip_runtime.h>
#include <hip/hip_fp16.h>

#define NNODES 100000
#define KNBR 32
#define IN_C 128
#define OUT_C 64

// ===========================================================================
// Kernel 1: h = x @ W^T via MFMA (bf16 hi/lo split, fp16 store)
// (unchanged — not the bottleneck; kept for clean attribution)
// ===========================================================================

typedef __attribute__((ext_vector_type(8))) short bf16x8;
typedef __attribute__((ext_vector_type(4))) float f32x4;

__device__ __forceinline__ unsigned short bf16_rne(float f) {
    unsigned u = __builtin_bit_cast(unsigned, f);
    u = (u + 0x7FFFu + ((u >> 16) & 1u)) >> 16;
    return (unsigned short)u;
}
__device__ __forceinline__ float bf16_f(unsigned short s) {
    unsigned u = ((unsigned)s) << 16;
    return __builtin_bit_cast(float, u);
}

__device__ __forceinline__ void split8(const float4& u, const float4& v,
                                       bf16x8& hi, bf16x8& lo) {
    const float f[8] = {u.x, u.y, u.z, u.w, v.x, v.y, v.z, v.w};
#pragma unroll
    for (int j = 0; j < 8; ++j) {
        const unsigned short hb = bf16_rne(f[j]);
        hi[j] = (short)hb;
        lo[j] = (short)bf16_rne(f[j] - bf16_f(hb));
    }
}

// W LDS row stride: 136 elems = 272 B = 17*16 B. Keeps b128 alignment and
// rotates the 16B slot by one per row -> <=2-way bank aliasing (free).
#define GW_LD 136

__global__ __launch_bounds__(256) void gemm_h_kernel(
    const float* __restrict__ x, const float* __restrict__ W,
    __half* __restrict__ h)
{
    __shared__ __align__(16) unsigned short swh[64 * GW_LD];
    __shared__ __align__(16) unsigned short swl[64 * GW_LD];

    const int t = threadIdx.x;

    // ---- stage W as bf16 hi/lo into LDS (once per block) ----
#pragma unroll
    for (int i = 0; i < 8; ++i) {
        const int e   = t + 256 * i;        // float4 index, 2048 total
        const int row = e >> 5;             // 32 float4s per 128-float row
        const int c4  = (e & 31) * 4;
        const float4 wv = *(const float4*)(W + row * IN_C + c4);
        ushort4 ph, pl;
        ph.x = bf16_rne(wv.x); pl.x = bf16_rne(wv.x - bf16_f(ph.x));
        ph.y = bf16_rne(wv.y); pl.y = bf16_rne(wv.y - bf16_f(ph.y));
        ph.z = bf16_rne(wv.z); pl.z = bf16_rne(wv.z - bf16_f(ph.z));
        ph.w = bf16_rne(wv.w); pl.w = bf16_rne(wv.w - bf16_f(ph.w));
        *(ushort4*)(swh + row * GW_LD + c4) = ph;
        *(ushort4*)(swl + row * GW_LD + c4) = pl;
    }
    __syncthreads();

    const int lane = t & 63;
    const int w    = t >> 6;
    const int r    = lane & 15;   // A-frag row / B-frag col / C-frag col
    const int g    = lane >> 4;   // k-chunk within frag (8 elems each)
    const int nb   = blockIdx.x * 128 + 32 * w;

    f32x4 acc[2][4];
#pragma unroll
    for (int i = 0; i < 2; ++i)
#pragma unroll
        for (int c = 0; c < 4; ++c) acc[i][c] = (f32x4){0.f, 0.f, 0.f, 0.f};

    int n0 = nb + r;       if (n0 > NNODES - 1) n0 = NNODES - 1;
    int n1 = nb + 16 + r;  if (n1 > NNODES - 1) n1 = NNODES - 1;
    const float* px0 = x + (size_t)n0 * IN_C;
    const float* px1 = x + (size_t)n1 * IN_C;

#pragma unroll
    for (int ks = 0; ks < 4; ++ks) {
        const int k0 = 32 * ks + 8 * g;
        const float4 u0 = *(const float4*)(px0 + k0);
        const float4 v0 = *(const float4*)(px0 + k0 + 4);
        const float4 u1 = *(const float4*)(px1 + k0);
        const float4 v1 = *(const float4*)(px1 + k0 + 4);
        bf16x8 a0h, a0l, a1h, a1l;
        split8(u0, v0, a0h, a0l);
        split8(u1, v1, a1h, a1l);
#pragma unroll
        for (int c = 0; c < 4; ++c) {
            const int wrow = 16 * c + r;
            const bf16x8 bh = *(const bf16x8*)(swh + wrow * GW_LD + k0);
            const bf16x8 bl = *(const bf16x8*)(swl + wrow * GW_LD + k0);
            acc[0][c] = __builtin_amdgcn_mfma_f32_16x16x32_bf16(a0h, bh, acc[0][c], 0, 0, 0);
            acc[1][c] = __builtin_amdgcn_mfma_f32_16x16x32_bf16(a1h, bh, acc[1][c], 0, 0, 0);
            acc[0][c] = __builtin_amdgcn_mfma_f32_16x16x32_bf16(a0l, bh, acc[0][c], 0, 0, 0);
            acc[1][c] = __builtin_amdgcn_mfma_f32_16x16x32_bf16(a1l, bh, acc[1][c], 0, 0, 0);
            acc[0][c] = __builtin_amdgcn_mfma_f32_16x16x32_bf16(a0h, bl, acc[0][c], 0, 0, 0);
            acc[1][c] = __builtin_amdgcn_mfma_f32_16x16x32_bf16(a1h, bl, acc[1][c], 0, 0, 0);
        }
    }

    // C layout (m89-verified): col = lane&15, row = (lane>>4)*4 + i
#pragma unroll
    for (int rf = 0; rf < 2; ++rf) {
#pragma unroll
        for (int i = 0; i < 4; ++i) {
            const int node = nb + 16 * rf + 4 * g + i;
            if (node < NNODES) {
                __half* ph = h + (size_t)node * OUT_C + r;
#pragma unroll
                for (int c = 0; c < 4; ++c)
                    ph[16 * c] = __float2half(acc[rf][c][i]);
            }
        }
    }
}

// ======================= Kernel 2: gather + rank-15-of-32 ==================
// Packed half2 min/max via gfx950 VOP3P — ROCm 7.2 headers lack __hmin2/__hmax2.
__device__ __forceinline__ unsigned pk_min(unsigned a, unsigned b) {
    unsigned d;
    asm("v_pk_min_f16 %0, %1, %2" : "=v"(d) : "v"(a), "v"(b));
    return d;
}
__device__ __forceinline__ unsigned pk_max(unsigned a, unsigned b) {
    unsigned d;
    asm("v_pk_max_f16 %0, %1, %2" : "=v"(d) : "v"(a), "v"(b));
    return d;
}
__device__ __forceinline__ void ce(unsigned& a, unsigned& b) {
    const unsigned lo = pk_min(a, b);
    b = pk_max(a, b);
    a = lo;
}

// Batcher odd-even mergesort, n=16, 63 comparators (hardcoded list).
__device__ __forceinline__ void sort16(unsigned* v) {
    constexpr unsigned char net[63][2] = {
        {0,1},{2,3},{4,5},{6,7},{8,9},{10,11},{12,13},{14,15},
        {0,2},{1,3},{4,6},{5,7},{8,10},{9,11},{12,14},{13,15},
        {1,2},{5,6},{9,10},{13,14},
        {0,4},{1,5},{2,6},{3,7},{8,12},{9,13},{10,14},{11,15},
        {2,4},{3,5},{10,12},{11,13},
        {1,2},{3,4},{5,6},{9,10},{11,12},{13,14},
        {0,8},{1,9},{2,10},{3,11},{4,12},{5,13},{6,14},{7,15},
        {4,8},{5,9},{6,10},{7,11},
        {2,4},{3,5},{6,8},{7,9},{10,12},{11,13},
        {1,2},{3,4},{5,6},{7,8},{9,10},{11,12},{13,14}
    };
#pragma unroll
    for (int i = 0; i < 63; ++i) ce(v[net[i][0]], v[net[i][1]]);
}

// rank 15 (0-indexed) of 32 values: sort both 16-halves, then a pruned
// Batcher odd-even merge that materializes only output 15.
__device__ __forceinline__ unsigned median32(unsigned* v) {
    sort16(v);
    sort16(v + 16);
    const unsigned* A = v;
    const unsigned* B = v + 16;
    const unsigned e2a = pk_max(pk_max(A[0], B[0]), pk_min(A[8],  B[8]));
    const unsigned o1a = pk_min(pk_max(A[4], B[4]), pk_min(A[12], B[12]));
    const unsigned Ep4 = pk_max(e2a, o1a);
    const unsigned e2b = pk_max(pk_max(A[2], B[2]), pk_min(A[10], B[10]));
    const unsigned o1b = pk_min(pk_max(A[6], B[6]), pk_min(A[14], B[14]));
    const unsigned Op3 = pk_min(e2b, o1b);
    const unsigned E8  = pk_max(Ep4, Op3);
    const unsigned e2c = pk_max(pk_max(A[1], B[1]), pk_min(A[9],  B[9]));
    const unsigned o1c = pk_min(pk_max(A[5], B[5]), pk_min(A[13], B[13]));
    const unsigned Ep4o = pk_max(e2c, o1c);
    const unsigned e2d = pk_max(pk_max(A[3], B[3]), pk_min(A[11], B[11]));
    const unsigned o1d = pk_min(pk_max(A[7], B[7]), pk_min(A[15], B[15]));
    const unsigned Op3o = pk_min(e2d, o1d);
    const unsigned O7  = pk_min(Ep4o, Op3o);
    return pk_min(E8, O7);
}

// 32 lanes per node; each lane owns 2 channels as ONE packed-half2 stream.
// Addressing: broadcast the PRE-SHIFTED row byte-offset (idx<<7) via raw
// ds_bpermute (the +4k folds into the DS offset immediate -> 0 VALU/k for
// lane addressing), then 1 v_add of the lane's hoisted channel offset and a
// SGPR-base + 32-bit-voffset global load. Per-k VALU cost: 1 instruction.
__global__ __launch_bounds__(256) void median_kernel(
    const __half* __restrict__ h, const int* __restrict__ nbrs,
    float* __restrict__ out)
{
    const int t = threadIdx.x;
    const int li   = t & 31;
    const int node = blockIdx.x * 8 + (t >> 5);

    const int idx  = nbrs[node * KNBR + li];   // coalesced: wave covers 2 nodes
    const int bval = idx << 7;                 // h-row byte offset (128 B rows)
    const int gbase = (t & 32) << 2;           // bpermute group base (byte addr)
    const unsigned chb = (unsigned)li << 2;    // channel byte offset: 2*li halves

    const unsigned char* hb = (const unsigned char*)h;

    unsigned a[KNBR];
#pragma unroll
    for (int k = 0; k < KNBR; ++k) {
        const unsigned ro = (unsigned)__builtin_amdgcn_ds_bpermute(gbase + 4 * k, bval);
        a[k] = *(const unsigned*)(hb + (ro + chb));
    }

    const unsigned m = median32(a);
    const __half2 hm = *(const __half2*)&m;
    float2 o;
    o.x = __low2float(hm);
    o.y = __high2float(hm);
    *(float2*)(out + node * OUT_C + 2 * li) = o;
}

extern "C" void kernel_launch(void* const* d_in, const int* in_sizes, int n_in,
                              void* d_out, int out_size, void* d_ws, size_t ws_size,
                              hipStream_t stream) {
    (void)in_sizes; (void)n_in; (void)out_size; (void)ws_size;
    const float* x    = (const float*)d_in[0];
    const int*   nbrs = (const int*)d_in[1];
    const float* W    = (const float*)d_in[2];
    float* out = (float*)d_out;
    __half* h  = (__half*)d_ws;   // 100000*64*2 = 12.8 MB scratch

    gemm_h_kernel<<<(NNODES + 127) / 128, 256, 0, stream>>>(x, W, h);
    median_kernel<<<NNODES / 8, 256, 0, stream>>>(h, nbrs, out);
}